// Round 16
// baseline (407.332 us; speedup 1.0000x reference)
//
#include <hip/hip_runtime.h>
#include <hip/hip_bf16.h>

// Problem constants: B=4, S=2048, D=1024, H=16, HD=64
#define S_LEN  2048
#define DMODEL 1024
#define NHEAD  16
#define HDIM   64
#define BSZ    4

// exp2-domain softmax constants
#define C_SCORE  0.18033688f        // 0.125 * log2(e)
#define C_MASK  -1.4426950e9f       // -1e9 * log2(e)

typedef __bf16 bf16_t;
typedef __bf16 bf16x8 __attribute__((ext_vector_type(8)));
typedef __bf16 bf16x4 __attribute__((ext_vector_type(4)));
typedef float  f32x4  __attribute__((ext_vector_type(4)));

typedef __attribute__((address_space(1))) void as1_void;
typedef __attribute__((address_space(3))) void as3_void;

__device__ __forceinline__ f32x4 mfma16(bf16x8 a, bf16x8 b, f32x4 c) {
    return __builtin_amdgcn_mfma_f32_16x16x32_bf16(a, b, c, 0, 0, 0);
}

// ---------------------------------------------------------------------------
// Merged conversion kernel: blocks [0,4096) convert x fp32->bf16; blocks
// [4096,5120) transpose+convert the 4 weight matrices into wT.
__global__ __launch_bounds__(256) void cvt_all(const float* __restrict__ x,
                                               bf16_t* __restrict__ xb,
                                               const float* __restrict__ w0,
                                               const float* __restrict__ w1,
                                               const float* __restrict__ w2,
                                               const float* __restrict__ w3,
                                               bf16_t* __restrict__ wT) {
    __shared__ bf16_t t[64][65];
    const int bid = blockIdx.x;
    if (bid < 4096) {
        const int i0 = bid * 256 + threadIdx.x;
        #pragma unroll
        for (int rep = 0; rep < 2; ++rep) {
            const int i = i0 + rep * 1048576;
            float4 v = ((const float4*)x)[i];
            bf16x4 tv = { (bf16_t)v.x, (bf16_t)v.y, (bf16_t)v.z, (bf16_t)v.w };
            ((bf16x4*)xb)[i] = tv;
        }
        return;
    }
    const int wb = bid - 4096;              // 0..1023
    const int wsel = wb >> 8;               // 0..3
    const float* w = wsel == 0 ? w0 : (wsel == 1 ? w1 : (wsel == 2 ? w2 : w3));
    bf16_t* wTo = wT + (size_t)wsel * DMODEL * DMODEL;
    const int rb = wb & 255;
    const int bx = (rb & 15) * 64, by = (rb >> 4) * 64;
    const int tx = threadIdx.x & 63, ty = threadIdx.x >> 6;
    #pragma unroll
    for (int rr = 0; rr < 64; rr += 4)
        t[tx][rr + ty] = (bf16_t)w[(size_t)(bx + rr + ty) * DMODEL + by + tx];
    __syncthreads();
    #pragma unroll
    for (int rr = 0; rr < 64; rr += 4)
        wTo[(size_t)(by + rr + ty) * DMODEL + bx + tx] = t[rr + ty][tx];
}

// ---------------------------------------------------------------------------
// GEMM: C = A(Mx1024) * Bt(Nx1024)^T + bias. 128x128 tile, 4 waves (2x2).
// MODE 0: fused QKV (N=3072): Q,K bf16 (B,H,S,HD) row-major; V written
//         TRANSPOSED (B,H,HD,S) via an LDS round-trip epilogue.
// MODE 2: out-projection (N=1024): fp32 (B,S,D).
template <int MODE>
__global__ __launch_bounds__(256) void gemm_bt(const bf16_t* __restrict__ A,
                                               const bf16_t* __restrict__ Bt,
                                               const float* __restrict__ b0,
                                               const float* __restrict__ b1,
                                               const float* __restrict__ b2,
                                               bf16_t* __restrict__ o0,
                                               bf16_t* __restrict__ o1,
                                               bf16_t* __restrict__ o2,
                                               float* __restrict__ of) {
    constexpr int GK = 1024;
    __shared__ __attribute__((aligned(16))) bf16_t smem_ab[8704];
    bf16_t* As = smem_ab;
    bf16_t* Bs = smem_ab + 4096;

    const int tid  = threadIdx.x;
    const int wave = tid >> 6, lane = tid & 63;
    const int col16 = lane & 15, g = lane >> 4;
    const int wr = wave >> 1, wc = wave & 1;
    const int bn0 = blockIdx.x * 128, bm0 = blockIdx.y * 128;

    const int r4 = tid >> 2;
    const int c8 = (tid & 3) * 8;

    f32x4 acc[4][4] = {};

    for (int k0 = 0; k0 < GK; k0 += 32) {
        __syncthreads();
        #pragma unroll
        for (int i = 0; i < 2; ++i) {
            __builtin_amdgcn_global_load_lds(
                (const as1_void*)(A + (size_t)(bm0 + i * 64 + r4) * GK + k0 + c8),
                (as3_void*)(As + (i * 64 + wave * 16) * 32), 16, 0, 0);
            __builtin_amdgcn_global_load_lds(
                (const as1_void*)(Bt + (size_t)(bn0 + i * 64 + r4) * GK + k0 + c8),
                (as3_void*)(Bs + (i * 64 + wave * 16) * 32), 16, 0, 0);
        }
        __syncthreads();

        bf16x8 af[4], bfr[4];
        #pragma unroll
        for (int i = 0; i < 4; ++i) {
            af[i]  = *(const bf16x8*)(As + (wr * 64 + i * 16 + col16) * 32 + g * 8);
            bfr[i] = *(const bf16x8*)(Bs + (wc * 64 + i * 16 + col16) * 32 + g * 8);
        }
        #pragma unroll
        for (int mi = 0; mi < 4; ++mi)
            #pragma unroll
            for (int ni = 0; ni < 4; ++ni)
                acc[mi][ni] = mfma16(af[mi], bfr[ni], acc[mi][ni]);
    }

    if (MODE == 0 && (bn0 >> 10) == 2) {
        // ---- V path: write V^T (B,H,HD,S) via LDS transpose ----
        const int n1base = bn0 - 2048;
        const int brow = bm0 >> 11;
        const int s0 = bm0 & 2047;
        __syncthreads();
        #pragma unroll
        for (int p = 0; p < 2; ++p) {
            if (p) __syncthreads();
            if (wc == p) {
                #pragma unroll
                for (int ni = 0; ni < 4; ++ni) {
                    const float bv = b2[n1base + p * 64 + ni * 16 + col16];
                    #pragma unroll
                    for (int mi = 0; mi < 4; ++mi) {
                        bf16x4 pv;
                        #pragma unroll
                        for (int r = 0; r < 4; ++r) pv[r] = (bf16_t)(acc[mi][ni][r] + bv);
                        *(bf16x4*)&smem_ab[(ni * 16 + col16) * 136 + wr * 64 + mi * 16 + g * 4] = pv;
                    }
                }
            }
            __syncthreads();
            const int h2 = (n1base + p * 64) >> 6;
            bf16_t* vout = o2 + (((size_t)brow * NHEAD + h2) * HDIM) * S_LEN + s0;
            #pragma unroll
            for (int j = 0; j < 4; ++j) {
                const int unit = j * 256 + tid;
                const int row = unit >> 4;
                const int cu = (unit & 15) * 8;
                bf16x8 v = *(const bf16x8*)&smem_ab[row * 136 + cu];
                *(bf16x8*)(vout + (size_t)row * S_LEN + cu) = v;
            }
        }
        return;
    }

    #pragma unroll
    for (int ni = 0; ni < 4; ++ni) {
        const int gn = bn0 + wc * 64 + ni * 16 + col16;
        if (MODE == 0) {
            const int proj = bn0 >> 10;
            const float* bias = proj == 0 ? b0 : b1;
            bf16_t* outp      = proj == 0 ? o0 : o1;
            const int n1 = gn & 1023, h = n1 >> 6, hd = n1 & 63;
            const float bv = bias[n1];
            #pragma unroll
            for (int mi = 0; mi < 4; ++mi)
                #pragma unroll
                for (int r = 0; r < 4; ++r) {
                    const int gm = bm0 + wr * 64 + mi * 16 + g * 4 + r;
                    const int b = gm >> 11, s = gm & 2047;
                    outp[(((size_t)b * NHEAD + h) * S_LEN + s) * HDIM + hd] =
                        (bf16_t)(acc[mi][ni][r] + bv);
                }
        } else {
            const float bv = b0[gn];
            #pragma unroll
            for (int mi = 0; mi < 4; ++mi)
                #pragma unroll
                for (int r = 0; r < 4; ++r) {
                    const int gm = bm0 + wr * 64 + mi * 16 + g * 4 + r;
                    of[(size_t)gm * DMODEL + gn] = acc[mi][ni][r] + bv;
                }
        }
    }
}

// ---------------------------------------------------------------------------
// Fused attention v16 = v14 (best: 369us) with ONE change: attnW stores are
// NORMAL cached stores instead of nontemporal. Rationale: nt bypasses L2 and
// acks at the HBM controller (full HBM latency per store, pacing coupled to
// controller jitter — v15's deeper slack didn't fix it). Normal stores ack at
// L2 (~200cy) and dirty lines drain to HBM in the background at the L2's
// eviction pace — the fire-and-forget behavior counted-vmcnt tried to
// emulate. The harness's own fillBuffer (plain stores, 10% occupancy) hits
// 6.5 TB/s on this same buffer; our nt path sat at ~4.6. L2 pollution is
// harmless: K/V reads total ~25 MB and are L3-resident.
// Everything else identical to v14 (8 waves x 16-row granularity, 2-tile,
// loop A 128-row chunks, loop BC with counted vmcnt(8)).
__global__ __launch_bounds__(512, 4) void attn_fused(const bf16_t* __restrict__ Q,
                                                     const bf16_t* __restrict__ K,
                                                     const bf16_t* __restrict__ Vt,
                                                     const float* __restrict__ mask,
                                                     float* __restrict__ attnW,
                                                     bf16_t* __restrict__ ctx) {
    __shared__ __attribute__((aligned(16))) char smem[73728];
    bf16_t (*KsA)[128][64] = (bf16_t(*)[128][64])smem;            // loop A view
    bf16_t (*Ks)[64][64]   = (bf16_t(*)[64][64])smem;             // BC view
    bf16_t (*Vs)[64][64]   = (bf16_t(*)[64][64])(smem + 16384);
    float  (*Pl)[16][64]   = (float(*)[16][64])(smem + 32768);
    float*  Ml             = (float*)(smem + 65536);

    const int tid = threadIdx.x, wave = tid >> 6, lane = tid & 63;
    const int col16 = lane & 15, g = lane >> 4;
    const int r7 = col16 & 7;

    // bijective XCD swizzle (512 blocks, 512 % 8 == 0): 8 heads per XCD
    const int lin = blockIdx.x;
    const int logical = (lin & 7) * 64 + (lin >> 3);
    const int bh = logical >> 3, pp = logical & 7;
    const int b = bh >> 4, h = bh & 15;
    const int qA = pp * 256 + wave * 16;
    const int qB = pp * 256 + 128 + wave * 16;

    const bf16_t* Qb = Q + (size_t)bh * S_LEN * HDIM;
    const bf16_t* Kb = K + (size_t)bh * S_LEN * HDIM;
    const bf16_t* Vb = Vt + (size_t)bh * HDIM * S_LEN;
    const float* mp = mask + (size_t)b * S_LEN;

    // mask * C_MASK -> LDS once (512 threads, 512 f32x4 slots)
    {
        f32x4 v = ((const f32x4*)mp)[tid];
        #pragma unroll
        for (int r = 0; r < 4; ++r) v[r] *= C_MASK;
        *(f32x4*)(&Ml[tid * 4]) = v;
    }

    // staging lane constants: linear LDS dest, pre-swizzled global source
    const int srow  = lane >> 3;
    const int sunit = (lane & 7) ^ srow;

    auto stageA = [&](int buf, int it) {       // 128 k-rows per buffer, 2/wave
        const int kk0 = it << 7;
        #pragma unroll
        for (int i2 = 0; i2 < 2; ++i2) {
            const int i = wave * 2 + i2;       // chunk 0..15 (8 rows each)
            __builtin_amdgcn_global_load_lds(
                (const as1_void*)(Kb + (size_t)(kk0 + i * 8 + srow) * HDIM + sunit * 8),
                (as3_void*)(&KsA[buf][i * 8][0]), 16, 0, 0);
        }
    };
    auto stageK = [&](int buf, int it) {       // 64 rows, 1 chunk/wave
        const int kk0 = it << 6;
        __builtin_amdgcn_global_load_lds(
            (const as1_void*)(Kb + (size_t)(kk0 + wave * 8 + srow) * HDIM + sunit * 8),
            (as3_void*)(&Ks[buf][wave * 8][0]), 16, 0, 0);
    };
    auto stageV = [&](int buf, int it) {
        const int kk0 = it << 6;
        __builtin_amdgcn_global_load_lds(
            (const as1_void*)(Vb + (size_t)(wave * 8 + srow) * S_LEN + kk0 + sunit * 8),
            (as3_void*)(&Vs[buf][wave * 8][0]), 16, 0, 0);
    };
    auto kfrag = [&](int buf, int nj, int kh) {
        return *(const bf16x8*)(&Ks[buf][nj * 16 + col16][(((kh * 4 + g) ^ r7) * 8)]);
    };
    auto vfrag = [&](int buf, int nd, int kh) {
        return *(const bf16x8*)(&Vs[buf][nd * 16 + col16][(((kh * 4 + g) ^ r7) * 8)]);
    };

    // Q B-frags: one 16-row group per tile
    bf16x8 qa0[2], qa1[2];
    #pragma unroll
    for (int kh = 0; kh < 2; ++kh) {
        qa0[kh] = *(const bf16x8*)(Qb + (size_t)(qA + col16) * HDIM + kh * 32 + g * 8);
        qa1[kh] = *(const bf16x8*)(Qb + (size_t)(qB + col16) * HDIM + kh * 32 + g * 8);
    }

    // ================= loop A: l(tile0) AND l(tile1), 128-row chunks =======
    f32x4 lacc0 = {}, lacc1 = {};
    stageA(0, 0);
    __syncthreads();   // Ml fill + stage(0) ready

    for (int it = 0; it < 16; ++it) {
        const int kk0 = it << 7, cur = it & 1;
        if (it < 15) stageA(cur ^ 1, it + 1);
        #pragma unroll
        for (int nj = 0; nj < 8; ++nj) {
            const f32x4 mvr = *(const f32x4*)(&Ml[kk0 + nj * 16 + g * 4]);
            const bf16x8 kf0 = *(const bf16x8*)(&KsA[cur][nj * 16 + col16][((g ^ r7) * 8)]);
            const bf16x8 kf1 = *(const bf16x8*)(&KsA[cur][nj * 16 + col16][(((4 + g) ^ r7) * 8)]);
            f32x4 t0 = {0.f, 0.f, 0.f, 0.f}, u0 = {0.f, 0.f, 0.f, 0.f};
            t0 = mfma16(kf0, qa0[0], t0);
            t0 = mfma16(kf1, qa0[1], t0);
            u0 = mfma16(kf0, qa1[0], u0);
            u0 = mfma16(kf1, qa1[1], u0);
            #pragma unroll
            for (int r = 0; r < 4; ++r) {
                lacc0[r] += exp2f(fmaf(t0[r], C_SCORE, mvr[r]));
                lacc1[r] += exp2f(fmaf(u0[r], C_SCORE, mvr[r]));
            }
        }
        asm volatile("s_waitcnt vmcnt(0)" ::: "memory");
        __builtin_amdgcn_sched_barrier(0);
        __builtin_amdgcn_s_barrier();
    }

    float crow0, crow1;
    {
        float lr0 = (lacc0[0] + lacc0[1]) + (lacc0[2] + lacc0[3]);
        lr0 += __shfl_xor(lr0, 16);
        lr0 += __shfl_xor(lr0, 32);
        crow0 = -__log2f(lr0);
        float lr1 = (lacc1[0] + lacc1[1]) + (lacc1[2] + lacc1[3]);
        lr1 += __shfl_xor(lr1, 16);
        lr1 += __shfl_xor(lr1, 32);
        crow1 = -__log2f(lr1);
    }

    // ================= loop BC: store(tile0) + store(tile1) =================
    f32x4 o0[4] = {}, o1[4] = {};
    float* awA = attnW + ((size_t)bh * S_LEN + qA) * S_LEN;
    float* awB = attnW + ((size_t)bh * S_LEN + qB) * S_LEN;

    stageK(0, 0);
    stageV(0, 0);
    asm volatile("s_waitcnt vmcnt(0)" ::: "memory");
    __builtin_amdgcn_sched_barrier(0);
    __builtin_amdgcn_s_barrier();

    for (int it = 0; it < 32; ++it) {
        const int kk0 = it << 6, cur = it & 1;
        if (it < 31) { stageK(cur ^ 1, it + 1); stageV(cur ^ 1, it + 1); }
        __builtin_amdgcn_sched_barrier(0);   // pin: stages issue before stores
        f32x4 mvr[4];
        #pragma unroll
        for (int nj = 0; nj < 4; ++nj)
            mvr[nj] = *(const f32x4*)(&Ml[kk0 + nj * 16 + g * 4]);

        // ---- tile0: QK^T -> exp2 -> Pl -> stores -> PV ----
        #pragma unroll
        for (int nj = 0; nj < 4; ++nj) {
            const bf16x8 kf0 = kfrag(cur, nj, 0);
            const bf16x8 kf1 = kfrag(cur, nj, 1);
            f32x4 s0 = {0.f, 0.f, 0.f, 0.f};
            s0 = mfma16(kf0, qa0[0], s0);
            s0 = mfma16(kf1, qa0[1], s0);
            f32x4 pn0;
            #pragma unroll
            for (int r = 0; r < 4; ++r)
                pn0[r] = exp2f(fmaf(s0[r], C_SCORE, mvr[nj][r] + crow0));
            *(f32x4*)(&Pl[wave][col16][(((nj * 4 + g) ^ r7) * 4)]) = pn0;
        }
        #pragma unroll
        for (int j = 0; j < 4; ++j) {
            const int row = j * 4 + (lane >> 4);
            const int u = lane & 15;
            const f32x4 v = *(const f32x4*)(&Pl[wave][row][((u ^ (row & 7)) * 4)]);
            *(f32x4*)(awA + (size_t)row * S_LEN + kk0 + u * 4) = v;   // cached store
        }
        #pragma unroll
        for (int kh = 0; kh < 2; ++kh) {
            const int u0i = kh * 8 + g * 2;
            const f32x4 a0 = *(const f32x4*)(&Pl[wave][col16][((u0i ^ r7) * 4)]);
            const f32x4 a1 = *(const f32x4*)(&Pl[wave][col16][(((u0i + 1) ^ r7) * 4)]);
            bf16x8 pa;
            #pragma unroll
            for (int j = 0; j < 4; ++j) {
                pa[j]     = (bf16_t)a0[j];
                pa[4 + j] = (bf16_t)a1[j];
            }
            #pragma unroll
            for (int nd = 0; nd < 4; ++nd)
                o0[nd] = mfma16(vfrag(cur, nd, kh), pa, o0[nd]);
        }

        // ---- tile1: same sequence, same Pl buffer (wave-private reuse) ----
        #pragma unroll
        for (int nj = 0; nj < 4; ++nj) {
            const bf16x8 kf0 = kfrag(cur, nj, 0);
            const bf16x8 kf1 = kfrag(cur, nj, 1);
            f32x4 s0 = {0.f, 0.f, 0.f, 0.f};
            s0 = mfma16(kf0, qa1[0], s0);
            s0 = mfma16(kf1, qa1[1], s0);
            f32x4 pn0;
            #pragma unroll
            for (int r = 0; r < 4; ++r)
                pn0[r] = exp2f(fmaf(s0[r], C_SCORE, mvr[nj][r] + crow1));
            *(f32x4*)(&Pl[wave][col16][(((nj * 4 + g) ^ r7) * 4)]) = pn0;
        }
        #pragma unroll
        for (int j = 0; j < 4; ++j) {
            const int row = j * 4 + (lane >> 4);
            const int u = lane & 15;
            const f32x4 v = *(const f32x4*)(&Pl[wave][row][((u ^ (row & 7)) * 4)]);
            *(f32x4*)(awB + (size_t)row * S_LEN + kk0 + u * 4) = v;   // cached store
        }
        #pragma unroll
        for (int kh = 0; kh < 2; ++kh) {
            const int u0i = kh * 8 + g * 2;
            const f32x4 a0 = *(const f32x4*)(&Pl[wave][col16][((u0i ^ r7) * 4)]);
            const f32x4 a1 = *(const f32x4*)(&Pl[wave][col16][(((u0i + 1) ^ r7) * 4)]);
            bf16x8 pa;
            #pragma unroll
            for (int j = 0; j < 4; ++j) {
                pa[j]     = (bf16_t)a0[j];
                pa[4 + j] = (bf16_t)a1[j];
            }
            #pragma unroll
            for (int nd = 0; nd < 4; ++nd)
                o1[nd] = mfma16(vfrag(cur, nd, kh), pa, o1[nd]);
        }

        // retire prev stores + this iter's 2 stages; keep 8 stores in flight
        asm volatile("s_waitcnt vmcnt(8)" ::: "memory");
        __builtin_amdgcn_sched_barrier(0);
        __builtin_amdgcn_s_barrier();
    }

    // ctx (both tiles): wave's 16 rows each
    {
        bf16_t* cpA = ctx + ((size_t)b * S_LEN + qA + col16) * DMODEL + h * HDIM;
        bf16_t* cpB = ctx + ((size_t)b * S_LEN + qB + col16) * DMODEL + h * HDIM;
        #pragma unroll
        for (int nd = 0; nd < 4; ++nd) {
            bf16x4 cv0, cv1;
            #pragma unroll
            for (int r = 0; r < 4; ++r) {
                cv0[r] = (bf16_t)o0[nd][r];
                cv1[r] = (bf16_t)o1[nd][r];
            }
            *(bf16x4*)(cpA + nd * 16 + g * 4) = cv0;
            *(bf16x4*)(cpB + nd * 16 + g * 4) = cv1;
        }
    }
}

// ---------------------------------------------------------------------------
extern "C" void kernel_launch(void* const* d_in, const int* in_sizes, int n_in,
                              void* d_out, int out_size, void* d_ws, size_t ws_size,
                              hipStream_t stream) {
    const float* x    = (const float*)d_in[0];
    const float* mask = (const float*)d_in[1];
    const float* wq   = (const float*)d_in[2];
    const float* bq   = (const float*)d_in[3];
    const float* wk   = (const float*)d_in[4];
    const float* bk   = (const float*)d_in[5];
    const float* wv   = (const float*)d_in[6];
    const float* bv   = (const float*)d_in[7];
    const float* wo   = (const float*)d_in[8];
    const float* bo   = (const float*)d_in[9];

    const size_t nX = (size_t)BSZ * S_LEN * DMODEL;      // 8388608
    const size_t nW = (size_t)DMODEL * DMODEL;           // 1048576

    char* ws = (char*)d_ws;
    size_t off = 0;
    bf16_t* xb     = (bf16_t*)(ws + off); off += nX * 2;
    bf16_t* wqkvT  = (bf16_t*)(ws + off); off += 3 * nW * 2;
    bf16_t* woT    = (bf16_t*)(ws + off); off += nW * 2;   // contiguous after wqkvT
    bf16_t* qbh    = (bf16_t*)(ws + off); off += nX * 2;
    bf16_t* kbh    = (bf16_t*)(ws + off); off += nX * 2;
    bf16_t* vtb    = (bf16_t*)(ws + off); off += nX * 2;
    bf16_t* ctx    = (bf16_t*)(ws + off); off += nX * 2;
    if (ws_size < off) return;  // workspace too small: loud failure (output stays zero)

    float* outp  = (float*)d_out;
    float* attnW = outp + nX;  // out is B*S*D, then attn weights B*H*S*S

    cvt_all<<<5120, 256, 0, stream>>>(x, xb, wq, wk, wv, wo, wqkvT);

    gemm_bt<0><<<dim3(24, 64), 256, 0, stream>>>(xb, wqkvT, bq, bk, bv,
                                                 qbh, kbh, vtb, nullptr);

    attn_fused<<<512, 512, 0, stream>>>(qbh, kbh, vtb, mask, attnW, ctx);

    gemm_bt<2><<<dim3(8, 64), 256, 0, stream>>>(ctx, woT, bo, nullptr, nullptr,
                                                nullptr, nullptr, nullptr, outp);
}

// Round 17
// 368.532 us; speedup vs baseline: 1.1053x; 1.1053x over previous
//
#include <hip/hip_runtime.h>
#include <hip/hip_bf16.h>

// Problem constants: B=4, S=2048, D=1024, H=16, HD=64
#define S_LEN  2048
#define DMODEL 1024
#define NHEAD  16
#define HDIM   64
#define BSZ    4

// exp2-domain softmax constants
#define C_SCORE  0.18033688f        // 0.125 * log2(e)
#define C_MASK  -1.4426950e9f       // -1e9 * log2(e)

typedef __bf16 bf16_t;
typedef __bf16 bf16x8 __attribute__((ext_vector_type(8)));
typedef __bf16 bf16x4 __attribute__((ext_vector_type(4)));
typedef float  f32x4  __attribute__((ext_vector_type(4)));

typedef __attribute__((address_space(1))) void as1_void;
typedef __attribute__((address_space(3))) void as3_void;

__device__ __forceinline__ f32x4 mfma16(bf16x8 a, bf16x8 b, f32x4 c) {
    return __builtin_amdgcn_mfma_f32_16x16x32_bf16(a, b, c, 0, 0, 0);
}

// ---------------------------------------------------------------------------
// Merged conversion kernel: blocks [0,4096) convert x fp32->bf16; blocks
// [4096,5120) transpose+convert the 4 weight matrices into wT.
__global__ __launch_bounds__(256) void cvt_all(const float* __restrict__ x,
                                               bf16_t* __restrict__ xb,
                                               const float* __restrict__ w0,
                                               const float* __restrict__ w1,
                                               const float* __restrict__ w2,
                                               const float* __restrict__ w3,
                                               bf16_t* __restrict__ wT) {
    __shared__ bf16_t t[64][65];
    const int bid = blockIdx.x;
    if (bid < 4096) {
        const int i0 = bid * 256 + threadIdx.x;
        #pragma unroll
        for (int rep = 0; rep < 2; ++rep) {
            const int i = i0 + rep * 1048576;
            float4 v = ((const float4*)x)[i];
            bf16x4 tv = { (bf16_t)v.x, (bf16_t)v.y, (bf16_t)v.z, (bf16_t)v.w };
            ((bf16x4*)xb)[i] = tv;
        }
        return;
    }
    const int wb = bid - 4096;              // 0..1023
    const int wsel = wb >> 8;               // 0..3
    const float* w = wsel == 0 ? w0 : (wsel == 1 ? w1 : (wsel == 2 ? w2 : w3));
    bf16_t* wTo = wT + (size_t)wsel * DMODEL * DMODEL;
    const int rb = wb & 255;
    const int bx = (rb & 15) * 64, by = (rb >> 4) * 64;
    const int tx = threadIdx.x & 63, ty = threadIdx.x >> 6;
    #pragma unroll
    for (int rr = 0; rr < 64; rr += 4)
        t[tx][rr + ty] = (bf16_t)w[(size_t)(bx + rr + ty) * DMODEL + by + tx];
    __syncthreads();
    #pragma unroll
    for (int rr = 0; rr < 64; rr += 4)
        wTo[(size_t)(by + rr + ty) * DMODEL + bx + tx] = t[rr + ty][tx];
}

// ---------------------------------------------------------------------------
// GEMM: C = A(Mx1024) * Bt(Nx1024)^T + bias. 128x128 tile, 4 waves (2x2).
// MODE 0: fused QKV (N=3072). Q,K written via LDS round-trip so every global
//         store is 1KB-contiguous bf16x8 (old path wrote 2B scalars = 32B
//         segments = 4-8x transaction amplification). V written TRANSPOSED
//         (B,H,HD,S) via the existing LDS epilogue.
// MODE 2: out-projection (N=1024): fp32 (B,S,D) via LDS round-trip chunks
//         (512B row segments instead of scalar 4B stores).
template <int MODE>
__global__ __launch_bounds__(256) void gemm_bt(const bf16_t* __restrict__ A,
                                               const bf16_t* __restrict__ Bt,
                                               const float* __restrict__ b0,
                                               const float* __restrict__ b1,
                                               const float* __restrict__ b2,
                                               bf16_t* __restrict__ o0,
                                               bf16_t* __restrict__ o1,
                                               bf16_t* __restrict__ o2,
                                               float* __restrict__ of) {
    constexpr int GK = 1024;
    __shared__ __attribute__((aligned(16))) bf16_t smem_ab[8704];
    bf16_t* As = smem_ab;
    bf16_t* Bs = smem_ab + 4096;

    const int tid  = threadIdx.x;
    const int wave = tid >> 6, lane = tid & 63;
    const int col16 = lane & 15, g = lane >> 4;
    const int wr = wave >> 1, wc = wave & 1;
    const int bn0 = blockIdx.x * 128, bm0 = blockIdx.y * 128;

    const int r4 = tid >> 2;
    const int c8 = (tid & 3) * 8;

    f32x4 acc[4][4] = {};

    for (int k0 = 0; k0 < GK; k0 += 32) {
        __syncthreads();
        #pragma unroll
        for (int i = 0; i < 2; ++i) {
            __builtin_amdgcn_global_load_lds(
                (const as1_void*)(A + (size_t)(bm0 + i * 64 + r4) * GK + k0 + c8),
                (as3_void*)(As + (i * 64 + wave * 16) * 32), 16, 0, 0);
            __builtin_amdgcn_global_load_lds(
                (const as1_void*)(Bt + (size_t)(bn0 + i * 64 + r4) * GK + k0 + c8),
                (as3_void*)(Bs + (i * 64 + wave * 16) * 32), 16, 0, 0);
        }
        __syncthreads();

        bf16x8 af[4], bfr[4];
        #pragma unroll
        for (int i = 0; i < 4; ++i) {
            af[i]  = *(const bf16x8*)(As + (wr * 64 + i * 16 + col16) * 32 + g * 8);
            bfr[i] = *(const bf16x8*)(Bs + (wc * 64 + i * 16 + col16) * 32 + g * 8);
        }
        #pragma unroll
        for (int mi = 0; mi < 4; ++mi)
            #pragma unroll
            for (int ni = 0; ni < 4; ++ni)
                acc[mi][ni] = mfma16(af[mi], bfr[ni], acc[mi][ni]);
    }

    if (MODE == 0) {
        const int proj = bn0 >> 10;
        const int brow = bm0 >> 11;
        const int s0 = bm0 & 2047;
        const int n1b = bn0 & 1023;

        if (proj == 2) {
            // ---- V path: write V^T (B,H,HD,S) via LDS transpose ----
            __syncthreads();
            #pragma unroll
            for (int p = 0; p < 2; ++p) {
                if (p) __syncthreads();
                if (wc == p) {
                    #pragma unroll
                    for (int ni = 0; ni < 4; ++ni) {
                        const float bv = b2[n1b + p * 64 + ni * 16 + col16];
                        #pragma unroll
                        for (int mi = 0; mi < 4; ++mi) {
                            bf16x4 pv;
                            #pragma unroll
                            for (int r = 0; r < 4; ++r) pv[r] = (bf16_t)(acc[mi][ni][r] + bv);
                            *(bf16x4*)&smem_ab[(ni * 16 + col16) * 136 + wr * 64 + mi * 16 + g * 4] = pv;
                        }
                    }
                }
                __syncthreads();
                const int h2 = (n1b + p * 64) >> 6;
                bf16_t* vout = o2 + (((size_t)brow * NHEAD + h2) * HDIM) * S_LEN + s0;
                #pragma unroll
                for (int j = 0; j < 4; ++j) {
                    const int unit = j * 256 + tid;
                    const int row = unit >> 4;
                    const int cu = (unit & 15) * 8;
                    bf16x8 v = *(const bf16x8*)&smem_ab[row * 136 + cu];
                    *(bf16x8*)(vout + (size_t)row * S_LEN + cu) = v;
                }
            }
            return;
        }

        // ---- Q/K path: LDS round-trip -> 1KB-contiguous bf16x8 stores ----
        const float* bias = proj == 0 ? b0 : b1;
        bf16_t* outp      = proj == 0 ? o0 : o1;
        __syncthreads();                       // K-loop LDS reads done
        #pragma unroll
        for (int p = 0; p < 2; ++p) {
            if (p) __syncthreads();            // prior read pass done
            if (wc == p) {
                #pragma unroll
                for (int ni = 0; ni < 4; ++ni) {
                    const float bv = bias[n1b + p * 64 + ni * 16 + col16];
                    #pragma unroll
                    for (int mi = 0; mi < 4; ++mi)
                        #pragma unroll
                        for (int r = 0; r < 4; ++r)
                            smem_ab[(wr * 64 + mi * 16 + g * 4 + r) * 64 + ni * 16 + col16] =
                                (bf16_t)(acc[mi][ni][r] + bv);
                }
            }
            __syncthreads();
            // smem [128][64] row-major == contiguous (s,hd) block in memory
            const int h2 = (n1b + p * 64) >> 6;
            bf16_t* qout = outp + (((size_t)brow * NHEAD + h2) * S_LEN + s0) * HDIM;
            #pragma unroll
            for (int pass = 0; pass < 4; ++pass) {
                const int idx = pass * 256 + tid;      // 16B units, 0..1023
                bf16x8 v = *(const bf16x8*)&smem_ab[idx * 8];
                *(bf16x8*)(qout + (size_t)idx * 8) = v;
            }
        }
        return;
    }

    // ---- MODE 2: fp32 out via LDS round-trip (512B row segments) ----
    {
        float* smem_f = (float*)smem_ab;       // [16][132] view (8448B)
        float bvr[4];
        #pragma unroll
        for (int ni = 0; ni < 4; ++ni)
            bvr[ni] = b0[bn0 + wc * 64 + ni * 16 + col16];
        __syncthreads();                       // K-loop LDS reads done
        #pragma unroll
        for (int c = 0; c < 8; ++c) {
            if (c) __syncthreads();            // prior read pass done
            if (wr == (c >> 2)) {
                const int mi = c & 3;
                #pragma unroll
                for (int ni = 0; ni < 4; ++ni)
                    #pragma unroll
                    for (int r = 0; r < 4; ++r)
                        smem_f[(g * 4 + r) * 132 + wc * 64 + ni * 16 + col16] =
                            acc[mi][ni][r] + bvr[ni];
            }
            __syncthreads();
            #pragma unroll
            for (int k2 = 0; k2 < 2; ++k2) {
                const int idx = k2 * 256 + tid;        // f32x4 units, 0..511
                const int row = idx >> 5, u = idx & 31;
                f32x4 v = *(const f32x4*)&smem_f[row * 132 + u * 4];
                *(f32x4*)(of + (size_t)(bm0 + c * 16 + row) * DMODEL + bn0 + u * 4) = v;
            }
        }
    }
}

// ---------------------------------------------------------------------------
// Fused attention v14 (best known: 369us): 8 waves x 16-row granularity,
// 2-tile, loop A 128-row chunks, loop BC with counted vmcnt(8), nt-stores.
__global__ __launch_bounds__(512, 4) void attn_fused(const bf16_t* __restrict__ Q,
                                                     const bf16_t* __restrict__ K,
                                                     const bf16_t* __restrict__ Vt,
                                                     const float* __restrict__ mask,
                                                     float* __restrict__ attnW,
                                                     bf16_t* __restrict__ ctx) {
    __shared__ __attribute__((aligned(16))) char smem[73728];
    bf16_t (*KsA)[128][64] = (bf16_t(*)[128][64])smem;            // loop A view
    bf16_t (*Ks)[64][64]   = (bf16_t(*)[64][64])smem;             // BC view
    bf16_t (*Vs)[64][64]   = (bf16_t(*)[64][64])(smem + 16384);
    float  (*Pl)[16][64]   = (float(*)[16][64])(smem + 32768);
    float*  Ml             = (float*)(smem + 65536);

    const int tid = threadIdx.x, wave = tid >> 6, lane = tid & 63;
    const int col16 = lane & 15, g = lane >> 4;
    const int r7 = col16 & 7;

    // bijective XCD swizzle (512 blocks, 512 % 8 == 0): 8 heads per XCD
    const int lin = blockIdx.x;
    const int logical = (lin & 7) * 64 + (lin >> 3);
    const int bh = logical >> 3, pp = logical & 7;
    const int b = bh >> 4, h = bh & 15;
    const int qA = pp * 256 + wave * 16;
    const int qB = pp * 256 + 128 + wave * 16;

    const bf16_t* Qb = Q + (size_t)bh * S_LEN * HDIM;
    const bf16_t* Kb = K + (size_t)bh * S_LEN * HDIM;
    const bf16_t* Vb = Vt + (size_t)bh * HDIM * S_LEN;
    const float* mp = mask + (size_t)b * S_LEN;

    // mask * C_MASK -> LDS once (512 threads, 512 f32x4 slots)
    {
        f32x4 v = ((const f32x4*)mp)[tid];
        #pragma unroll
        for (int r = 0; r < 4; ++r) v[r] *= C_MASK;
        *(f32x4*)(&Ml[tid * 4]) = v;
    }

    // staging lane constants: linear LDS dest, pre-swizzled global source
    const int srow  = lane >> 3;
    const int sunit = (lane & 7) ^ srow;

    auto stageA = [&](int buf, int it) {       // 128 k-rows per buffer, 2/wave
        const int kk0 = it << 7;
        #pragma unroll
        for (int i2 = 0; i2 < 2; ++i2) {
            const int i = wave * 2 + i2;       // chunk 0..15 (8 rows each)
            __builtin_amdgcn_global_load_lds(
                (const as1_void*)(Kb + (size_t)(kk0 + i * 8 + srow) * HDIM + sunit * 8),
                (as3_void*)(&KsA[buf][i * 8][0]), 16, 0, 0);
        }
    };
    auto stageK = [&](int buf, int it) {       // 64 rows, 1 chunk/wave
        const int kk0 = it << 6;
        __builtin_amdgcn_global_load_lds(
            (const as1_void*)(Kb + (size_t)(kk0 + wave * 8 + srow) * HDIM + sunit * 8),
            (as3_void*)(&Ks[buf][wave * 8][0]), 16, 0, 0);
    };
    auto stageV = [&](int buf, int it) {
        const int kk0 = it << 6;
        __builtin_amdgcn_global_load_lds(
            (const as1_void*)(Vb + (size_t)(wave * 8 + srow) * S_LEN + kk0 + sunit * 8),
            (as3_void*)(&Vs[buf][wave * 8][0]), 16, 0, 0);
    };
    auto kfrag = [&](int buf, int nj, int kh) {
        return *(const bf16x8*)(&Ks[buf][nj * 16 + col16][(((kh * 4 + g) ^ r7) * 8)]);
    };
    auto vfrag = [&](int buf, int nd, int kh) {
        return *(const bf16x8*)(&Vs[buf][nd * 16 + col16][(((kh * 4 + g) ^ r7) * 8)]);
    };

    // Q B-frags: one 16-row group per tile
    bf16x8 qa0[2], qa1[2];
    #pragma unroll
    for (int kh = 0; kh < 2; ++kh) {
        qa0[kh] = *(const bf16x8*)(Qb + (size_t)(qA + col16) * HDIM + kh * 32 + g * 8);
        qa1[kh] = *(const bf16x8*)(Qb + (size_t)(qB + col16) * HDIM + kh * 32 + g * 8);
    }

    // ================= loop A: l(tile0) AND l(tile1), 128-row chunks =======
    f32x4 lacc0 = {}, lacc1 = {};
    stageA(0, 0);
    __syncthreads();   // Ml fill + stage(0) ready

    for (int it = 0; it < 16; ++it) {
        const int kk0 = it << 7, cur = it & 1;
        if (it < 15) stageA(cur ^ 1, it + 1);
        #pragma unroll
        for (int nj = 0; nj < 8; ++nj) {
            const f32x4 mvr = *(const f32x4*)(&Ml[kk0 + nj * 16 + g * 4]);
            const bf16x8 kf0 = *(const bf16x8*)(&KsA[cur][nj * 16 + col16][((g ^ r7) * 8)]);
            const bf16x8 kf1 = *(const bf16x8*)(&KsA[cur][nj * 16 + col16][(((4 + g) ^ r7) * 8)]);
            f32x4 t0 = {0.f, 0.f, 0.f, 0.f}, u0 = {0.f, 0.f, 0.f, 0.f};
            t0 = mfma16(kf0, qa0[0], t0);
            t0 = mfma16(kf1, qa0[1], t0);
            u0 = mfma16(kf0, qa1[0], u0);
            u0 = mfma16(kf1, qa1[1], u0);
            #pragma unroll
            for (int r = 0; r < 4; ++r) {
                lacc0[r] += exp2f(fmaf(t0[r], C_SCORE, mvr[r]));
                lacc1[r] += exp2f(fmaf(u0[r], C_SCORE, mvr[r]));
            }
        }
        asm volatile("s_waitcnt vmcnt(0)" ::: "memory");
        __builtin_amdgcn_sched_barrier(0);
        __builtin_amdgcn_s_barrier();
    }

    float crow0, crow1;
    {
        float lr0 = (lacc0[0] + lacc0[1]) + (lacc0[2] + lacc0[3]);
        lr0 += __shfl_xor(lr0, 16);
        lr0 += __shfl_xor(lr0, 32);
        crow0 = -__log2f(lr0);
        float lr1 = (lacc1[0] + lacc1[1]) + (lacc1[2] + lacc1[3]);
        lr1 += __shfl_xor(lr1, 16);
        lr1 += __shfl_xor(lr1, 32);
        crow1 = -__log2f(lr1);
    }

    // ================= loop BC: store(tile0) + store(tile1) =================
    f32x4 o0[4] = {}, o1[4] = {};
    float* awA = attnW + ((size_t)bh * S_LEN + qA) * S_LEN;
    float* awB = attnW + ((size_t)bh * S_LEN + qB) * S_LEN;

    stageK(0, 0);
    stageV(0, 0);
    asm volatile("s_waitcnt vmcnt(0)" ::: "memory");
    __builtin_amdgcn_sched_barrier(0);
    __builtin_amdgcn_s_barrier();

    for (int it = 0; it < 32; ++it) {
        const int kk0 = it << 6, cur = it & 1;
        if (it < 31) { stageK(cur ^ 1, it + 1); stageV(cur ^ 1, it + 1); }
        __builtin_amdgcn_sched_barrier(0);   // pin: stages issue before stores
        f32x4 mvr[4];
        #pragma unroll
        for (int nj = 0; nj < 4; ++nj)
            mvr[nj] = *(const f32x4*)(&Ml[kk0 + nj * 16 + g * 4]);

        // ---- tile0: QK^T -> exp2 -> Pl -> stores -> PV ----
        #pragma unroll
        for (int nj = 0; nj < 4; ++nj) {
            const bf16x8 kf0 = kfrag(cur, nj, 0);
            const bf16x8 kf1 = kfrag(cur, nj, 1);
            f32x4 s0 = {0.f, 0.f, 0.f, 0.f};
            s0 = mfma16(kf0, qa0[0], s0);
            s0 = mfma16(kf1, qa0[1], s0);
            f32x4 pn0;
            #pragma unroll
            for (int r = 0; r < 4; ++r)
                pn0[r] = exp2f(fmaf(s0[r], C_SCORE, mvr[nj][r] + crow0));
            *(f32x4*)(&Pl[wave][col16][(((nj * 4 + g) ^ r7) * 4)]) = pn0;
        }
        #pragma unroll
        for (int j = 0; j < 4; ++j) {
            const int row = j * 4 + (lane >> 4);
            const int u = lane & 15;
            const f32x4 v = *(const f32x4*)(&Pl[wave][row][((u ^ (row & 7)) * 4)]);
            __builtin_nontemporal_store(v, (f32x4*)(awA + (size_t)row * S_LEN + kk0 + u * 4));
        }
        #pragma unroll
        for (int kh = 0; kh < 2; ++kh) {
            const int u0i = kh * 8 + g * 2;
            const f32x4 a0 = *(const f32x4*)(&Pl[wave][col16][((u0i ^ r7) * 4)]);
            const f32x4 a1 = *(const f32x4*)(&Pl[wave][col16][(((u0i + 1) ^ r7) * 4)]);
            bf16x8 pa;
            #pragma unroll
            for (int j = 0; j < 4; ++j) {
                pa[j]     = (bf16_t)a0[j];
                pa[4 + j] = (bf16_t)a1[j];
            }
            #pragma unroll
            for (int nd = 0; nd < 4; ++nd)
                o0[nd] = mfma16(vfrag(cur, nd, kh), pa, o0[nd]);
        }

        // ---- tile1: same sequence, same Pl buffer (wave-private reuse) ----
        #pragma unroll
        for (int nj = 0; nj < 4; ++nj) {
            const bf16x8 kf0 = kfrag(cur, nj, 0);
            const bf16x8 kf1 = kfrag(cur, nj, 1);
            f32x4 s0 = {0.f, 0.f, 0.f, 0.f};
            s0 = mfma16(kf0, qa1[0], s0);
            s0 = mfma16(kf1, qa1[1], s0);
            f32x4 pn0;
            #pragma unroll
            for (int r = 0; r < 4; ++r)
                pn0[r] = exp2f(fmaf(s0[r], C_SCORE, mvr[nj][r] + crow1));
            *(f32x4*)(&Pl[wave][col16][(((nj * 4 + g) ^ r7) * 4)]) = pn0;
        }
        #pragma unroll
        for (int j = 0; j < 4; ++j) {
            const int row = j * 4 + (lane >> 4);
            const int u = lane & 15;
            const f32x4 v = *(const f32x4*)(&Pl[wave][row][((u ^ (row & 7)) * 4)]);
            __builtin_nontemporal_store(v, (f32x4*)(awB + (size_t)row * S_LEN + kk0 + u * 4));
        }
        #pragma unroll
        for (int kh = 0; kh < 2; ++kh) {
            const int u0i = kh * 8 + g * 2;
            const f32x4 a0 = *(const f32x4*)(&Pl[wave][col16][((u0i ^ r7) * 4)]);
            const f32x4 a1 = *(const f32x4*)(&Pl[wave][col16][(((u0i + 1) ^ r7) * 4)]);
            bf16x8 pa;
            #pragma unroll
            for (int j = 0; j < 4; ++j) {
                pa[j]     = (bf16_t)a0[j];
                pa[4 + j] = (bf16_t)a1[j];
            }
            #pragma unroll
            for (int nd = 0; nd < 4; ++nd)
                o1[nd] = mfma16(vfrag(cur, nd, kh), pa, o1[nd]);
        }

        // retire prev stores + this iter's 2 stages; keep 8 stores in flight
        asm volatile("s_waitcnt vmcnt(8)" ::: "memory");
        __builtin_amdgcn_sched_barrier(0);
        __builtin_amdgcn_s_barrier();
    }

    // ctx (both tiles): wave's 16 rows each
    {
        bf16_t* cpA = ctx + ((size_t)b * S_LEN + qA + col16) * DMODEL + h * HDIM;
        bf16_t* cpB = ctx + ((size_t)b * S_LEN + qB + col16) * DMODEL + h * HDIM;
        #pragma unroll
        for (int nd = 0; nd < 4; ++nd) {
            bf16x4 cv0, cv1;
            #pragma unroll
            for (int r = 0; r < 4; ++r) {
                cv0[r] = (bf16_t)o0[nd][r];
                cv1[r] = (bf16_t)o1[nd][r];
            }
            *(bf16x4*)(cpA + nd * 16 + g * 4) = cv0;
            *(bf16x4*)(cpB + nd * 16 + g * 4) = cv1;
        }
    }
}

// ---------------------------------------------------------------------------
extern "C" void kernel_launch(void* const* d_in, const int* in_sizes, int n_in,
                              void* d_out, int out_size, void* d_ws, size_t ws_size,
                              hipStream_t stream) {
    const float* x    = (const float*)d_in[0];
    const float* mask = (const float*)d_in[1];
    const float* wq   = (const float*)d_in[2];
    const float* bq   = (const float*)d_in[3];
    const float* wk   = (const float*)d_in[4];
    const float* bk   = (const float*)d_in[5];
    const float* wv   = (const float*)d_in[6];
    const float* bv   = (const float*)d_in[7];
    const float* wo   = (const float*)d_in[8];
    const float* bo   = (const float*)d_in[9];

    const size_t nX = (size_t)BSZ * S_LEN * DMODEL;      // 8388608
    const size_t nW = (size_t)DMODEL * DMODEL;           // 1048576

    char* ws = (char*)d_ws;
    size_t off = 0;
    bf16_t* xb     = (bf16_t*)(ws + off); off += nX * 2;
    bf16_t* wqkvT  = (bf16_t*)(ws + off); off += 3 * nW * 2;
    bf16_t* woT    = (bf16_t*)(ws + off); off += nW * 2;   // contiguous after wqkvT
    bf16_t* qbh    = (bf16_t*)(ws + off); off += nX * 2;
    bf16_t* kbh    = (bf16_t*)(ws + off); off += nX * 2;
    bf16_t* vtb    = (bf16_t*)(ws + off); off += nX * 2;
    bf16_t* ctx    = (bf16_t*)(ws + off); off += nX * 2;
    if (ws_size < off) return;  // workspace too small: loud failure (output stays zero)

    float* outp  = (float*)d_out;
    float* attnW = outp + nX;  // out is B*S*D, then attn weights B*H*S*S

    cvt_all<<<5120, 256, 0, stream>>>(x, xb, wq, wk, wv, wo, wqkvT);

    gemm_bt<0><<<dim3(24, 64), 256, 0, stream>>>(xb, wqkvT, bq, bk, bv,
                                                 qbh, kbh, vtb, nullptr);

    attn_fused<<<512, 512, 0, stream>>>(qbh, kbh, vtb, mask, attnW, ctx);

    gemm_bt<2><<<dim3(8, 64), 256, 0, stream>>>(ctx, woT, bo, nullptr, nullptr,
                                                nullptr, nullptr, nullptr, outp);
}